// Round 5
// baseline (630.206 us; speedup 1.0000x reference)
//
#include <hip/hip_runtime.h>
#include <math.h>

// DILATE loss, MI355X. B=256, N=336, V=7, fp32.
// R5: 4 waves per block (one per SIMD), each wave owns 84 columns,
// lane owns CW=2 columns (42 active lanes). Wave-synchronous anti-diagonal
// wavefront inside each wave (shuffles); cross-wave boundary columns via
// LDS value+flag producer-consumer handoff (read-ahead 2). Backward R
// readback uses a depth-4 register prefetch. Per-cell math identical to R4.

#define BATCH 256
#define SEQN 336
#define NV 7
#define BIGF 1e8f
#define WAVES 4
#define LPW 42                    // active lanes per wave
#define CW 2                      // columns per lane
#define CPW (LPW * CW)            // 84 columns per wave
#define TPAD 9
#define NSTEP (SEQN + LPW - 1)    // 377

__global__ __launch_bounds__(256) void dilate_fused(const float* __restrict__ outputs,
                                                    const float* __restrict__ targets,
                                                    float* __restrict__ Rg,
                                                    float* __restrict__ partial) {
    __shared__ float t_lds[SEQN][TPAD];
    __shared__ float xn_lds[SEQN];
    __shared__ float bndR[WAVES - 1][SEQN];
    __shared__ int   flagF[WAVES - 1][SEQN];
    __shared__ float bndE[WAVES - 1][SEQN];
    __shared__ float bndRr[WAVES - 1][SEQN];
    __shared__ float bndD[WAVES - 1][SEQN];
    __shared__ int   flagB[WAVES - 1][SEQN];
    __shared__ float redbuf[WAVES];

    const int b = blockIdx.x;
    const int tid = threadIdx.x;
    const int w = tid >> 6;
    const int l = tid & 63;
    const int j0 = w * CPW + l * CW;

    const float* tb = targets + (size_t)b * SEQN * NV;
    const float* ob = outputs + (size_t)b * SEQN * NV;

    // stage t rows (coalesced) + zero handoff flags
    for (int k = tid; k < SEQN * NV; k += 256) {
        int r = k / NV, c = k - r * NV;
        t_lds[r][c] = tb[k];
    }
    for (int k = tid; k < (WAVES - 1) * SEQN; k += 256) {
        ((int*)flagF)[k] = 0;
        ((int*)flagB)[k] = 0;
    }
    __syncthreads();
    for (int i = tid; i < SEQN; i += 256) {
        float s = 0.f;
#pragma unroll
        for (int v = 0; v < NV; ++v) { float x = t_lds[i][v]; s = fmaf(x, x, s); }
        xn_lds[i] = s;
    }
    __syncthreads();

    // own output columns -> registers
    float o_reg[CW][NV];
    float yn[CW];
    if (l < LPW) {
#pragma unroll
        for (int c = 0; c < CW; ++c) {
            float s = 0.f;
#pragma unroll
            for (int v = 0; v < NV; ++v) {
                float y = ob[(size_t)(j0 + c) * NV + v];
                o_reg[c][v] = y;
                s = fmaf(y, y, s);
            }
            yn[c] = s;
        }
    }

    float* Rb = Rg + (size_t)b * SEQN * SEQN;

    // ---------------- forward ----------------
    float Rprev0 = BIGF, Rprev1 = BIGF;   // R[i-1][j0], R[i-1][j0+1]
    float pubR0 = BIGF, pubR1 = BIGF;
    float lB0 = BIGF, lB1 = BIGF, dB = BIGF;

    if (w > 0) {  // prefetch boundary rows 0,1
        while (*(volatile int*)&flagF[w - 1][0] == 0) {}
        __asm__ __volatile__("" ::: "memory");
        lB0 = bndR[w - 1][0];
        while (*(volatile int*)&flagF[w - 1][1] == 0) {}
        __asm__ __volatile__("" ::: "memory");
        lB1 = bndR[w - 1][1];
    }

#pragma unroll 1
    for (int s = 0; s < NSTEP; ++s) {
        float shR0 = __shfl_up(pubR0, 1);
        float shR1 = __shfl_up(pubR1, 1);

        float myLeft = BIGF, myDiag = BIGF;
        if (w > 0 && s <= SEQN - 1) {   // lane 0's row is i = s
            myLeft = lB0;
            myDiag = dB;
            dB = lB0;
            lB0 = lB1;
            if (s + 2 <= SEQN - 1) {
                while (*(volatile int*)&flagF[w - 1][s + 2] == 0) {}
                __asm__ __volatile__("" ::: "memory");
                lB1 = bndR[w - 1][s + 2];
            }
        }

        const int i = s - l;
        if (l < LPW && i >= 0 && i < SEQN) {
            float tv[NV];
#pragma unroll
            for (int v = 0; v < NV; ++v) tv[v] = t_lds[i][v];
            float xni = xn_lds[i];

            float left, diag;
            if (l == 0) {
                if (w == 0) { left = BIGF; diag = (i == 0) ? 0.f : BIGF; }
                else        { left = myLeft; diag = (i == 0) ? BIGF : myDiag; }
            } else {
                left = shR0;
                diag = (i == 0) ? BIGF : shR1;
            }
            float up0 = (i == 0) ? BIGF : Rprev0;
            float up1 = (i == 0) ? BIGF : Rprev1;

            // c = 0
            float dot0 = 0.f;
#pragma unroll
            for (int v = 0; v < NV; ++v) dot0 = fmaf(tv[v], o_reg[0][v], dot0);
            float dist0 = fmaxf(xni + yn[0] - 2.f * dot0, 0.f);
            float m0 = fminf(diag, fminf(up0, left));
            float es0 = __expf(m0 - diag) + __expf(m0 - up0) + __expf(m0 - left);
            float r0 = dist0 + m0 - __logf(es0);

            // c = 1: diag1 = up0, left1 = r0
            float dot1 = 0.f;
#pragma unroll
            for (int v = 0; v < NV; ++v) dot1 = fmaf(tv[v], o_reg[1][v], dot1);
            float dist1 = fmaxf(xni + yn[1] - 2.f * dot1, 0.f);
            float m1 = fminf(up0, fminf(up1, r0));
            float es1 = __expf(m1 - up0) + __expf(m1 - up1) + __expf(m1 - r0);
            float r1 = dist1 + m1 - __logf(es1);

            *(float2*)(Rb + (size_t)i * SEQN + j0) = make_float2(r0, r1);

            if (w < WAVES - 1 && l == LPW - 1) {   // publish boundary col 84w+83
                bndR[w][i] = r1;
                __asm__ __volatile__("s_waitcnt lgkmcnt(0)" ::: "memory");
                *(volatile int*)&flagF[w][i] = 1;
            }
            pubR1 = up1;   // R[i-1][j0+1]
            pubR0 = r1;    // R[i][j0+1]
            Rprev0 = r0;
            Rprev1 = r1;
        }
    }

    __syncthreads();

    // ---------------- backward ----------------
    float Pe0 = 0.f, Pe1 = 0.f, Pr0 = 0.f, Pr1 = 0.f, Pd0 = 0.f, Pd1 = 0.f;
    float pubE0 = 0.f, pubRr0 = 0.f, pubD0 = 0.f;
    float pubE1 = 0.f, pubRr1 = 0.f, pubD1 = 0.f;
    float acc = 0.f;

    // boundary queue (consumer: wave w < 3 reads wave w+1's col 84(w+1))
    float tE0 = 0.f, tR0 = 0.f, tD0 = 0.f;
    float tE1 = 0.f, tR1 = 0.f, tD1 = 0.f;
    float pE = 0.f, pR = 0.f, pD = 0.f;
    if (w < WAVES - 1) {
        while (*(volatile int*)&flagB[w][SEQN - 1] == 0) {}
        __asm__ __volatile__("" ::: "memory");
        tE0 = bndE[w][SEQN - 1]; tR0 = bndRr[w][SEQN - 1]; tD0 = bndD[w][SEQN - 1];
        while (*(volatile int*)&flagB[w][SEQN - 2] == 0) {}
        __asm__ __volatile__("" ::: "memory");
        tE1 = bndE[w][SEQN - 2]; tR1 = bndRr[w][SEQN - 2]; tD1 = bndD[w][SEQN - 2];
    }

    auto ldrow = [&](int s) -> float2 {
        const int i = (NSTEP - 1) - s - l;
        if (l < LPW && i >= 0 && i < SEQN)
            return *(const float2*)(Rb + (size_t)i * SEQN + j0);
        return make_float2(0.f, 0.f);
    };

    auto bstep = [&](int s, float2 q) {
        float shE0 = __shfl_down(pubE0, 1);
        float shR0 = __shfl_down(pubRr0, 1);
        float shD0 = __shfl_down(pubD0, 1);
        float shE1 = __shfl_down(pubE1, 1);
        float shR1 = __shfl_down(pubRr1, 1);
        float shD1 = __shfl_down(pubD1, 1);

        float bRtE = 0.f, bRtR = 0.f, bRtD = 0.f;
        float bDgE = 0.f, bDgR = 0.f, bDgD = 0.f;
        if (w < WAVES - 1 && s <= SEQN - 1) {   // lane 41's row is i = 335 - s
            bRtE = tE0; bRtR = tR0; bRtD = tD0;
            bDgE = pE;  bDgR = pR;  bDgD = pD;
            pE = tE0; pR = tR0; pD = tD0;
            tE0 = tE1; tR0 = tR1; tD0 = tD1;
            if (s + 2 <= SEQN - 1) {
                const int r = SEQN - 1 - (s + 2);
                while (*(volatile int*)&flagB[w][r] == 0) {}
                __asm__ __volatile__("" ::: "memory");
                tE1 = bndE[w][r]; tR1 = bndRr[w][r]; tD1 = bndD[w][r];
            }
        }

        const int i = (NSTEP - 1) - s - l;
        if (l < LPW && i >= 0 && i < SEQN) {
            float tv[NV];
#pragma unroll
            for (int v = 0; v < NV; ++v) tv[v] = t_lds[i][v];
            float xni = xn_lds[i];

            float Ert, Rrt, Drt, Edg, Rdg, Ddg;
            if (l == LPW - 1) {
                if (w == WAVES - 1) { Ert = 0.f; Rrt = 0.f; Drt = 0.f; Edg = 0.f; Rdg = 0.f; Ddg = 0.f; }
                else { Ert = bRtE; Rrt = bRtR; Drt = bRtD; Edg = bDgE; Rdg = bDgR; Ddg = bDgD; }
            } else {
                Ert = shE0; Rrt = shR0; Drt = shD0;
                Edg = shE1; Rdg = shR1; Ddg = shD1;
            }

            // c = 1 (right cell first)
            float rcur1 = q.y;
            float dot1 = 0.f;
#pragma unroll
            for (int v = 0; v < NV; ++v) dot1 = fmaf(tv[v], o_reg[1][v], dot1);
            float d1 = fmaxf(xni + yn[1] - 2.f * dot1, 0.f);
            float wA1 = __expf(Pr1 - rcur1 - Pd1) * Pe1;   // down  (i+1, j0+1)
            float wB1 = __expf(Rrt - rcur1 - Drt) * Ert;   // right (i,   j0+2)
            float wC1 = __expf(Rdg - rcur1 - Ddg) * Edg;   // diag  (i+1, j0+2)
            float e1 = wA1 + wB1 + wC1;
            if (w == WAVES - 1 && l == LPW - 1 && i == SEQN - 1) e1 = 1.f;
            float f1 = (float)(i - (j0 + 1));
            acc = fmaf(e1, f1 * f1, acc);

            // c = 0: right = this row's c=1; diag = old P*1 (row i+1, j0+1)
            float rcur0 = q.x;
            float dot0 = 0.f;
#pragma unroll
            for (int v = 0; v < NV; ++v) dot0 = fmaf(tv[v], o_reg[0][v], dot0);
            float d0 = fmaxf(xni + yn[0] - 2.f * dot0, 0.f);
            float wA0 = __expf(Pr0 - rcur0 - Pd0) * Pe0;     // down  (i+1, j0)
            float wB0 = __expf(rcur1 - rcur0 - d1) * e1;     // right (i,   j0+1)
            float wC0 = __expf(Pr1 - rcur0 - Pd1) * Pe1;     // diag  (i+1, j0+1), old P1
            float e0 = wA0 + wB0 + wC0;
            float f0v = (float)(i - j0);
            acc = fmaf(e0, f0v * f0v, acc);

            if (w > 0 && l == 0) {   // publish boundary col 84w
                bndE[w - 1][i] = e0; bndRr[w - 1][i] = rcur0; bndD[w - 1][i] = d0;
                __asm__ __volatile__("s_waitcnt lgkmcnt(0)" ::: "memory");
                *(volatile int*)&flagB[w - 1][i] = 1;
            }

            float oE = pubE0, oR = pubRr0, oD = pubD0;
            pubE0 = e0; pubRr0 = rcur0; pubD0 = d0;
            pubE1 = oE; pubRr1 = oR;  pubD1 = oD;
            Pe1 = e1; Pr1 = rcur1; Pd1 = d1;
            Pe0 = e0; Pr0 = rcur0; Pd0 = d0;
        }
    };

    float2 q0 = ldrow(0), q1 = ldrow(1), q2 = ldrow(2), q3 = ldrow(3);
#pragma unroll 1
    for (int s = 0; s + 3 < NSTEP; s += 4) {
        bstep(s, q0);     q0 = ldrow(s + 4);
        bstep(s + 1, q1); q1 = ldrow(s + 5);
        bstep(s + 2, q2); q2 = ldrow(s + 6);
        bstep(s + 3, q3); q3 = ldrow(s + 7);
    }
    bstep(NSTEP - 1, q0);   // 377 = 94*4 + 1

    // reduce acc: wave shuffle + cross-wave via LDS
#pragma unroll
    for (int off = 32; off > 0; off >>= 1) acc += __shfl_xor(acc, off);
    if (l == 0) redbuf[w] = acc;
    __syncthreads();
    if (tid == 0) partial[b] = redbuf[0] + redbuf[1] + redbuf[2] + redbuf[3];
}

__global__ __launch_bounds__(BATCH) void finish_kernel(const float* __restrict__ Rg,
                                                       const float* __restrict__ partial,
                                                       float* __restrict__ out) {
    __shared__ float s1[BATCH];
    __shared__ float s2[BATCH];
    const int t = threadIdx.x;
    s1[t] = Rg[(size_t)t * SEQN * SEQN + (size_t)(SEQN - 1) * SEQN + (SEQN - 1)];
    s2[t] = partial[t];
    __syncthreads();
    for (int off = BATCH / 2; off > 0; off >>= 1) {
        if (t < off) { s1[t] += s1[t + off]; s2[t] += s2[t + off]; }
        __syncthreads();
    }
    if (t == 0) {
        float loss_shape = s1[0] / (float)BATCH;
        float denom = (float)SEQN * (float)SEQN * (float)BATCH * (float)BATCH;
        float loss_temporal = s2[0] / denom;
        out[0] = 0.5f * loss_shape + 0.5f * loss_temporal;
    }
}

extern "C" void kernel_launch(void* const* d_in, const int* in_sizes, int n_in,
                              void* d_out, int out_size, void* d_ws, size_t ws_size,
                              hipStream_t stream) {
    const float* outputs = (const float*)d_in[0];
    const float* targets = (const float*)d_in[1];
    float* out = (float*)d_out;

    float* Rg = (float*)d_ws;                              // 256*336*336 floats
    float* partial = Rg + (size_t)BATCH * SEQN * SEQN;     // 256 floats

    dilate_fused<<<BATCH, 256, 0, stream>>>(outputs, targets, Rg, partial);
    finish_kernel<<<1, BATCH, 0, stream>>>(Rg, partial, out);
}

// Round 6
// 407.695 us; speedup vs baseline: 1.5458x; 1.5458x over previous
//
#include <hip/hip_runtime.h>
#include <math.h>

// DILATE loss, MI355X. B=256, N=336, V=7, fp32. One wave per batch,
// wave-synchronous anti-diagonal wavefront (no barriers in DP loops).
// Lane l owns columns [6l, 6l+6); 56 active lanes. R6 chain cuts:
//  - base-2 domain (R' = R/ln2): native exp2/log2, no dependent muls
//  - 1 shfl/step fwd, 3/step bwd (diag values = previous step's shfl)
//  - software-pipelined t-row/xn prefetch (ds latency off the chain)
//  - fixed R4's bwd remainder-step bug (388/389 skipped)

#define BATCH 256
#define SEQN 336
#define NV 7
#define BIGF 1e8f
#define NLANE 56
#define CW 6
#define TPAD 9
#define NSTEP (SEQN + NLANE - 1)  // 391
#define INV_LN2 1.44269504088896f
#define LN2 0.693147180559945f

#if __has_builtin(__builtin_amdgcn_exp2f)
#define EXP2F(x) __builtin_amdgcn_exp2f(x)
#else
#define EXP2F(x) __expf((x) * LN2)
#endif
#if __has_builtin(__builtin_amdgcn_logf)
#define LOG2F(x) __builtin_amdgcn_logf(x)   // v_log_f32 = log2(x)
#else
#define LOG2F(x) (__logf(x) * INV_LN2)
#endif

struct R6v { float v[CW]; };

__global__ __launch_bounds__(64) void dilate_fused(const float* __restrict__ outputs,
                                                   const float* __restrict__ targets,
                                                   float* __restrict__ Rg,
                                                   float* __restrict__ partial) {
    __shared__ float t_lds[SEQN][TPAD];
    __shared__ float xn_lds[SEQN];

    const int b = blockIdx.x;
    const int l = threadIdx.x;
    const float* tb = targets + (size_t)b * SEQN * NV;
    const float* ob = outputs + (size_t)b * SEQN * NV;

    for (int k = l; k < SEQN * NV; k += 64) {
        int r = k / NV, c = k - r * NV;
        t_lds[r][c] = tb[k];
    }
    __syncthreads();
    for (int i = l; i < SEQN; i += 64) {
        float s = 0.f;
#pragma unroll
        for (int v = 0; v < NV; ++v) { float x = t_lds[i][v]; s = fmaf(x, x, s); }
        xn_lds[i] = s;
    }
    __syncthreads();

    // own output columns -> registers
    float o_reg[CW][NV];
    float yn[CW];
    if (l < NLANE) {
        const float* op = ob + (size_t)l * CW * NV;
#pragma unroll
        for (int c = 0; c < CW; ++c) {
            float s = 0.f;
#pragma unroll
            for (int v = 0; v < NV; ++v) {
                float y = op[c * NV + v];
                o_reg[c][v] = y;
                s = fmaf(y, y, s);
            }
            yn[c] = s;
        }
    }

    float* Rb = Rg + (size_t)b * SEQN * SEQN;

    // ---------------- forward (R' = R/ln2 domain) ----------------
    float Rprev[CW];
#pragma unroll
    for (int c = 0; c < CW; ++c) Rprev[c] = BIGF;
    float pubR0 = BIGF;      // my R'[i][j0+5] (published for lane l+1)
    float prevSh = BIGF;     // shfl received last step (lane l-1, row i-1)

    float tvc[NV], xnc;
#pragma unroll
    for (int v = 0; v < NV; ++v) tvc[v] = t_lds[0][v];
    xnc = xn_lds[0];

#pragma unroll 1
    for (int s = 0; s < NSTEP; ++s) {
        float shL = __shfl_up(pubR0, 1);
        const int i = s - l;
        const int inx = i + 1;
        float tvn[NV]; float xnn = 0.f;
        bool pf = (l < NLANE) && (inx >= 0) && (inx < SEQN);
        if (pf) {
#pragma unroll
            for (int v = 0; v < NV; ++v) tvn[v] = t_lds[inx][v];
            xnn = xn_lds[inx];
        }
        if (l < NLANE && i >= 0 && i < SEQN) {
            float left = (l == 0) ? BIGF : shL;
            float diag;
            if (l == 0) diag = (i == 0) ? 0.f : BIGF;
            else        diag = (i == 0) ? BIGF : prevSh;
            float rout[CW];
#pragma unroll
            for (int c = 0; c < CW; ++c) {
                float up = (i == 0) ? BIGF : Rprev[c];
                float dot = 0.f;
#pragma unroll
                for (int v = 0; v < NV; ++v) dot = fmaf(tvc[v], o_reg[c][v], dot);
                float dist = fmaxf(xnc + yn[c] - 2.f * dot, 0.f) * INV_LN2;  // D'
                float m = fminf(diag, fminf(up, left));
                float es = EXP2F(m - diag) + EXP2F(m - up) + EXP2F(m - left);
                float r = dist + m - LOG2F(es);
                rout[c] = r;
                diag = up;
                Rprev[c] = r;
                left = r;
            }
            float2* pst = (float2*)(Rb + (size_t)i * SEQN + (size_t)l * CW);
            pst[0] = make_float2(rout[0], rout[1]);
            pst[1] = make_float2(rout[2], rout[3]);
            pst[2] = make_float2(rout[4], rout[5]);
            pubR0 = rout[5];
        }
        prevSh = shL;
#pragma unroll
        for (int v = 0; v < NV; ++v) tvc[v] = tvn[v];
        xnc = xnn;
    }

    __syncthreads();   // drains vmcnt: R stores visible to own reloads

    // ---------------- backward ----------------
    float Pe[CW], Pr[CW], Pd[CW];
#pragma unroll
    for (int c = 0; c < CW; ++c) { Pe[c] = 0.f; Pr[c] = 0.f; Pd[c] = 0.f; }
    float pubE0 = 0.f, pubRr0 = 0.f, pubD0 = 0.f;      // my (i, j0) values
    float prevE = 0.f, prevR = 0.f, prevD = 0.f;       // shfl from last step
    float acc = 0.f;

#pragma unroll
    for (int v = 0; v < NV; ++v) tvc[v] = t_lds[SEQN - 1][v];
    xnc = xn_lds[SEQN - 1];

    auto ldrow6 = [&](int s) -> R6v {
        R6v r;
        const int i = (NSTEP - 1) - s - l;
        if (l < NLANE && i >= 0 && i < SEQN) {
            const float2* p = (const float2*)(Rb + (size_t)i * SEQN + (size_t)l * CW);
            float2 a = p[0], b2 = p[1], c2 = p[2];
            r.v[0] = a.x;  r.v[1] = a.y;
            r.v[2] = b2.x; r.v[3] = b2.y;
            r.v[4] = c2.x; r.v[5] = c2.y;
        } else {
#pragma unroll
            for (int c = 0; c < CW; ++c) r.v[c] = 0.f;
        }
        return r;
    };

    auto bstep = [&](int s, const R6v& rb) {
        float shE = __shfl_down(pubE0, 1);
        float shR = __shfl_down(pubRr0, 1);
        float shD = __shfl_down(pubD0, 1);
        const int i = (NSTEP - 1) - s - l;
        const int inx = i - 1;
        float tvn[NV]; float xnn = 0.f;
        bool pf = (l < NLANE) && (inx >= 0) && (inx < SEQN);
        if (pf) {
#pragma unroll
            for (int v = 0; v < NV; ++v) tvn[v] = t_lds[inx][v];
            xnn = xn_lds[inx];
        }
        if (l < NLANE && i >= 0 && i < SEQN) {
            float Ert = shE,   Rrt = shR,   Drt = shD;     // right-succ (i, j+1)
            float Edg = prevE, Rdg = prevR, Ddg = prevD;   // diag-succ (i+1, j+1)
            float f0 = (float)(i - l * CW);
#pragma unroll
            for (int c = CW - 1; c >= 0; --c) {
                float rcur = rb.v[c];
                float dot = 0.f;
#pragma unroll
                for (int v = 0; v < NV; ++v) dot = fmaf(tvc[v], o_reg[c][v], dot);
                float dcur = fmaxf(xnc + yn[c] - 2.f * dot, 0.f) * INV_LN2;  // D'
                float wA = EXP2F(Pr[c] - rcur - Pd[c]) * Pe[c];   // down  (i+1, j)
                float wB = EXP2F(Rrt  - rcur - Drt ) * Ert;       // right (i, j+1)
                float wC = EXP2F(Rdg  - rcur - Ddg ) * Edg;       // diag  (i+1, j+1)
                float e = wA + wB + wC;
                if (c == CW - 1 && l == NLANE - 1 && i == SEQN - 1) e = 1.f;
                float diff = f0 - (float)c;
                acc = fmaf(e, diff * diff, acc);
                Ert = e;      Rrt = rcur;  Drt = dcur;
                Edg = Pe[c];  Rdg = Pr[c]; Ddg = Pd[c];
                Pe[c] = e;    Pr[c] = rcur; Pd[c] = dcur;
            }
            pubE0 = Ert; pubRr0 = Rrt; pubD0 = Drt;   // (i, j0) values
        }
        prevE = shE; prevR = shR; prevD = shD;
#pragma unroll
        for (int v = 0; v < NV; ++v) tvc[v] = tvn[v];
        xnc = xnn;
    };

    R6v q0 = ldrow6(0), q1 = ldrow6(1), q2 = ldrow6(2), q3 = ldrow6(3);
    int s = 0;
#pragma unroll 1
    for (; s + 3 < NSTEP; s += 4) {
        bstep(s, q0);     q0 = ldrow6(s + 4);
        bstep(s + 1, q1); q1 = ldrow6(s + 5);
        bstep(s + 2, q2); q2 = ldrow6(s + 6);
        bstep(s + 3, q3); q3 = ldrow6(s + 7);
    }
    // NSTEP = 391 -> s = 388 here; remaining steps 388, 389, 390
    bstep(s, q0);
    bstep(s + 1, q1);
    bstep(s + 2, q2);

#pragma unroll
    for (int off = 32; off > 0; off >>= 1) acc += __shfl_xor(acc, off);
    if (l == 0) partial[b] = acc;
}

__global__ __launch_bounds__(BATCH) void finish_kernel(const float* __restrict__ Rg,
                                                       const float* __restrict__ partial,
                                                       float* __restrict__ out) {
    __shared__ float s1[BATCH];
    __shared__ float s2[BATCH];
    const int t = threadIdx.x;
    s1[t] = Rg[(size_t)t * SEQN * SEQN + (size_t)(SEQN - 1) * SEQN + (SEQN - 1)];
    s2[t] = partial[t];
    __syncthreads();
    for (int off = BATCH / 2; off > 0; off >>= 1) {
        if (t < off) { s1[t] += s1[t + off]; s2[t] += s2[t + off]; }
        __syncthreads();
    }
    if (t == 0) {
        float loss_shape = s1[0] * LN2 / (float)BATCH;   // undo base-2 scaling
        float denom = (float)SEQN * (float)SEQN * (float)BATCH * (float)BATCH;
        float loss_temporal = s2[0] / denom;
        out[0] = 0.5f * loss_shape + 0.5f * loss_temporal;
    }
}

extern "C" void kernel_launch(void* const* d_in, const int* in_sizes, int n_in,
                              void* d_out, int out_size, void* d_ws, size_t ws_size,
                              hipStream_t stream) {
    const float* outputs = (const float*)d_in[0];
    const float* targets = (const float*)d_in[1];
    float* out = (float*)d_out;

    float* Rg = (float*)d_ws;                              // 256*336*336 floats
    float* partial = Rg + (size_t)BATCH * SEQN * SEQN;     // 256 floats

    dilate_fused<<<BATCH, 64, 0, stream>>>(outputs, targets, Rg, partial);
    finish_kernel<<<1, BATCH, 0, stream>>>(Rg, partial, out);
}